// Round 2
// baseline (499.233 us; speedup 1.0000x reference)
//
#include <hip/hip_runtime.h>

typedef __attribute__((ext_vector_type(4))) float f32x4;
typedef __attribute__((ext_vector_type(8))) short bf16x8;
typedef __attribute__((ext_vector_type(4))) short bf16x4;

// v_mfma_f32_16x16x16_bf16 (gfx950) is exposed via the gfx90a-era "_1k" builtin.
// Host pass can't see amdgcn builtins -> expand to (c) there (parse-only).
#if defined(__HIP_DEVICE_COMPILE__)
#define MFMA16(a,b,c) __builtin_amdgcn_mfma_f32_16x16x16bf16_1k(a,b,c,0,0,0)
#else
#define MFMA16(a,b,c) (c)
#endif

static __device__ __forceinline__ float bf2f(short s){
    unsigned int u = ((unsigned int)(unsigned short)s) << 16;
    return __builtin_bit_cast(float, u);
}
static __device__ __forceinline__ short f2bf(float f){
    unsigned int u = __builtin_bit_cast(unsigned int, f);
    unsigned int r = (u + 0x7fffu + ((u >> 16) & 1u)) >> 16;
    return (short)r;
}
static __device__ __forceinline__ void gload_lds16(const void* g, void* l){
    __builtin_amdgcn_global_load_lds((const __attribute__((address_space(1))) void*)g,
                                     (__attribute__((address_space(3))) void*)l, 16, 0, 0);
}

// ---------------- elementwise cast fp32 -> bf16 ----------------
__global__ __launch_bounds__(256) void cast_f32_bf16(const float* __restrict__ in,
                                                     short* __restrict__ out, long n){
    long i = ((long)blockIdx.x * 256 + threadIdx.x) * 8;
    if (i >= n) return;
    f32x4 a = *(const f32x4*)(in + i);
    f32x4 b = *(const f32x4*)(in + i + 4);
    bf16x8 o;
#pragma unroll
    for (int j = 0; j < 4; j++){ o[j] = f2bf(a[j]); o[4 + j] = f2bf(b[j]); }
    *(bf16x8*)(out + i) = o;
}

// ---------------- weight transpose-cast: w[K][N] -> wT[N][K] bf16 ----------------
__global__ __launch_bounds__(256) void transcast(const float* __restrict__ w,
                                                 short* __restrict__ wT, int K, int N){
    int n = blockIdx.x * 256 + threadIdx.x;
    int k0 = blockIdx.y * 8;
    bf16x8 o;
#pragma unroll
    for (int j = 0; j < 8; j++) o[j] = f2bf(w[(long)(k0 + j) * N + n]);
    *(bf16x8*)(wT + (long)n * K + k0) = o;
}

// ---------------- GEMM: C[M,N] = A[M,K](bf16) @ Bt[N,K]^T(bf16) + bias ----------------
// 128x128 tile, BK=32, 4 waves (2x2), 16x16x32 MFMA, global_load_lds staging with
// 16B-block XOR swizzle (blk ^= row&3) applied on the *global source* (rule #21).
__global__ __launch_bounds__(256, 2) void gemm_bf16(
    const short* __restrict__ A, const short* __restrict__ Bt, const float* __restrict__ bias,
    short* __restrict__ Cbf, float* __restrict__ Cf, int M, int N, int K, int doRelu)
{
    __shared__ __attribute__((aligned(16))) short lA[128 * 32];
    __shared__ __attribute__((aligned(16))) short lB[128 * 32];
    int t = threadIdx.x, w = t >> 6, l = t & 63;
    int cl = l & 15, g = l >> 4;
    long r0 = (long)blockIdx.y * 128, c0 = (long)blockIdx.x * 128;
    int wr = w >> 1, wc = w & 1;
    f32x4 acc[4][4];
#pragma unroll
    for (int mi = 0; mi < 4; mi++)
#pragma unroll
        for (int ni = 0; ni < 4; ni++) acc[mi][ni] = f32x4{0.f, 0.f, 0.f, 0.f};
    int srow = t >> 2, sblk = t & 3;
    for (int k0 = 0; k0 < K; k0 += 32){
        __syncthreads();
#pragma unroll
        for (int i = 0; i < 2; i++){
            int rrow = srow + i * 64;
            int sb = sblk ^ (rrow & 3);
            gload_lds16(A + (r0 + rrow) * (long)K + k0 + sb * 8, (char*)lA + i * 4096 + w * 1024);
            gload_lds16(Bt + (c0 + rrow) * (long)K + k0 + sb * 8, (char*)lB + i * 4096 + w * 1024);
        }
        __syncthreads();
        bf16x8 af[4], bfr[4];
#pragma unroll
        for (int mi = 0; mi < 4; mi++){
            int row = wr * 64 + mi * 16 + cl;
            af[mi] = *(const bf16x8*)(lA + row * 32 + (g ^ (row & 3)) * 8);
        }
#pragma unroll
        for (int ni = 0; ni < 4; ni++){
            int row = wc * 64 + ni * 16 + cl;
            bfr[ni] = *(const bf16x8*)(lB + row * 32 + (g ^ (row & 3)) * 8);
        }
#pragma unroll
        for (int mi = 0; mi < 4; mi++)
#pragma unroll
            for (int ni = 0; ni < 4; ni++)
                acc[mi][ni] = __builtin_amdgcn_mfma_f32_16x16x32_bf16(af[mi], bfr[ni], acc[mi][ni], 0, 0, 0);
    }
#pragma unroll
    for (int mi = 0; mi < 4; mi++)
#pragma unroll
        for (int ni = 0; ni < 4; ni++){
            long col = c0 + wc * 64 + ni * 16 + cl;
            float bv = bias[col];
#pragma unroll
            for (int rr = 0; rr < 4; rr++){
                long rowg = r0 + wr * 64 + mi * 16 + g * 4 + rr;
                float v = acc[mi][ni][rr] + bv;
                if (doRelu) v = fmaxf(v, 0.f);
                long idx = rowg * N + col;
                if (Cbf) Cbf[idx] = f2bf(v);
                if (Cf)  Cf[idx]  = v;
            }
        }
}

// ---------------- SA fuse: Qa/Ka = (qkv q/k) + (pos q/k), head-split [bh][qn][64] ----------------
__global__ __launch_bounds__(256) void fuse_sa_qk(const short* __restrict__ qkv,
                                                  const short* __restrict__ pos,
                                                  short* __restrict__ Qa, short* __restrict__ Ka){
    long i = (long)blockIdx.x * 256 + threadIdx.x;   // 8192*64 threads
    long row = i >> 6;
    int c = (int)(i & 63) * 8;
    int h = c >> 6, d = c & 63;
    long b = row >> 10, qn = row & 1023;
    long obase = ((b * 8 + h) * 1024 + qn) * 64 + d;
    bf16x8 q  = *(const bf16x8*)(qkv + row * 1536 + c);
    bf16x8 k  = *(const bf16x8*)(qkv + row * 1536 + 512 + c);
    bf16x8 qp = *(const bf16x8*)(pos + row * 1024 + c);
    bf16x8 kp = *(const bf16x8*)(pos + row * 1024 + 512 + c);
    bf16x8 oq, ok;
#pragma unroll
    for (int j = 0; j < 8; j++){
        oq[j] = f2bf(bf2f(q[j]) + bf2f(qp[j]));
        ok[j] = f2bf(bf2f(k[j]) + bf2f(kp[j]));
    }
    *(bf16x8*)(Qa + obase) = oq;
    *(bf16x8*)(Ka + obase) = ok;
}

// ---------------- V transpose: Vt[bh][dv=64][KN] from src[b*KN+kn][srcStride], col colBase+h*64+dv ----------------
__global__ __launch_bounds__(256) void fuse_vt(const short* __restrict__ src, short* __restrict__ Vt,
                                               int srcStride, int colBase, int KN){
    long bh = blockIdx.y; long b = bh >> 3; int h = (int)bh & 7;
    int dv = threadIdx.x & 63;
    int kn0 = blockIdx.x * 32 + (threadIdx.x >> 6) * 8;
    long base = (b * (long)KN + kn0) * srcStride + colBase + h * 64 + dv;
    bf16x8 o;
#pragma unroll
    for (int j = 0; j < 8; j++) o[j] = src[base + (long)j * srcStride];
    *(bf16x8*)(Vt + (bh * 64 + dv) * (long)KN + kn0) = o;
}

// ---------------- per-head concat: out[bh][n][128] = [a_head(64) | p_head(64)] ----------------
__global__ __launch_bounds__(256) void fuse_cat(const short* __restrict__ abuf,
                                                const short* __restrict__ pbuf,
                                                short* __restrict__ out,
                                                int SN, int snShift, int aStride, int pStride){
    long i = (long)blockIdx.x * 256 + threadIdx.x;
    long bh = i >> (4 + snShift);
    long n = (i >> 4) & (SN - 1);
    int c = ((int)i & 15) * 8;
    long b = bh >> 3; int h = (int)bh & 7;
    const short* s = (c < 64) ? (abuf + (b * SN + n) * (long)aStride + h * 64 + c)
                              : (pbuf + (b * SN + n) * (long)pStride + h * 64 + (c - 64));
    *(bf16x8*)(out + i * 8) = *(const bf16x8*)s;
}

// ---------------- fused residual + LayerNorm (512 cols), wave-per-row ----------------
__global__ __launch_bounds__(256) void ln_fuse(const float* __restrict__ a, const float* __restrict__ b,
                                               const float* __restrict__ g, const float* __restrict__ be,
                                               float* __restrict__ outf, short* __restrict__ outb){
    int w = threadIdx.x >> 6, l = threadIdx.x & 63;
    long row = (long)blockIdx.x * 4 + w;
    long base = row * 512 + l * 8;
    f32x4 a0 = *(const f32x4*)(a + base);
    f32x4 a1 = *(const f32x4*)(a + base + 4);
    f32x4 b0 = *(const f32x4*)(b + base);
    f32x4 b1 = *(const f32x4*)(b + base + 4);
    float x[8]; float s = 0.f, s2 = 0.f;
#pragma unroll
    for (int j = 0; j < 4; j++){ x[j] = a0[j] + b0[j]; x[4 + j] = a1[j] + b1[j]; }
#pragma unroll
    for (int j = 0; j < 8; j++){ s += x[j]; s2 += x[j] * x[j]; }
#pragma unroll
    for (int o = 1; o < 64; o <<= 1){ s += __shfl_xor(s, o); s2 += __shfl_xor(s2, o); }
    float mean = s * (1.f / 512.f);
    float rstd = rsqrtf(s2 * (1.f / 512.f) - mean * mean + 1e-5f);
    int c = l * 8;
    f32x4 y0, y1; bf16x8 ob;
#pragma unroll
    for (int j = 0; j < 4; j++){
        float y = (x[j] - mean) * rstd * g[c + j] + be[c + j];
        y0[j] = y; ob[j] = f2bf(y);
    }
#pragma unroll
    for (int j = 0; j < 4; j++){
        float y = (x[4 + j] - mean) * rstd * g[c + 4 + j] + be[c + 4 + j];
        y1[j] = y; ob[4 + j] = f2bf(y);
    }
    *(f32x4*)(outf + base) = y0;
    *(f32x4*)(outf + base + 4) = y1;
    if (outb) *(bf16x8*)(outb + base) = ob;
}

// ---------------- flash attention ----------------
// Q[bh][Qn][DH], K[bh][KN][DH], Vt[bh][64][KN] (bf16), out[b][q][h*64+dv] fp32.
// 4 waves/block, wave owns 16 q-rows; KT=64 key tiles; S^T = mfma16(K, Q) so the P
// C-layout coincides with the PV A-layout (no shuffles). XOR-swizzled LDS tiles.
template<int DH, int KN>
__global__ __launch_bounds__(256, 2) void attn_kernel(
    const short* __restrict__ Q, const short* __restrict__ K, const short* __restrict__ Vt,
    const unsigned char* __restrict__ mask, float* __restrict__ out, float scale)
{
    constexpr int KT = 64, DV = 64, Qn = 1024, H = 8;
    constexpr int NF = DH / 16;
    constexpr int KB = KT * DH * 2 / 4096;   // K-tile staging insts (2 or 4)
    constexpr int BPR = DH / 8;              // 16B blocks per K row
    __shared__ __attribute__((aligned(16))) short lK[KT * DH];
    __shared__ __attribute__((aligned(16))) short lV[DV * KT];
    int t = threadIdx.x, w = t >> 6, l = t & 63;
    int cl = l & 15, g = l >> 4;
    int bh = blockIdx.y; int b = bh >> 3; int h = bh & 7;
    int q0 = blockIdx.x * 64 + w * 16;
    bf16x4 qf[NF];
    {
        const short* qbase = Q + ((long)bh * Qn + q0) * DH;
#pragma unroll
        for (int f = 0; f < NF; f++)
            qf[f] = *(const bf16x4*)(qbase + (long)cl * DH + f * 16 + 4 * g);
    }
    const unsigned char* mrow = mask + (long)b * KN;
    float m = -1e30f, ssum = 0.f;
    f32x4 oacc[4];
#pragma unroll
    for (int dvc = 0; dvc < 4; dvc++) oacc[dvc] = f32x4{0.f, 0.f, 0.f, 0.f};

    for (int key0 = 0; key0 < KN; key0 += KT){
        __syncthreads();
#pragma unroll
        for (int i = 0; i < KB; i++){
            int slot = i * 256 + t;
            int row = slot / BPR, blk = slot % BPR;
            int sb = blk ^ (row & 7);
            gload_lds16(K + ((long)bh * KN + key0 + row) * DH + sb * 8, (char*)lK + i * 4096 + w * 1024);
        }
#pragma unroll
        for (int i = 0; i < 2; i++){
            int slot = i * 256 + t;
            int row = slot >> 3, blk = slot & 7;
            int sb = blk ^ (row & 7);
            gload_lds16(Vt + ((long)bh * DV + row) * KN + key0 + sb * 8, (char*)lV + i * 4096 + w * 1024);
        }
        __syncthreads();
        // S^T tiles: st[kg] lane holds S^T[key=kg*16+4g+rr][q=q0+cl]
        f32x4 st[4];
#pragma unroll
        for (int kg = 0; kg < 4; kg++){
            f32x4 acc = f32x4{0.f, 0.f, 0.f, 0.f};
            int krow = kg * 16 + cl;
#pragma unroll
            for (int f = 0; f < NF; f++){
                int sb = (2 * f + (g >> 1)) ^ (krow & 7);
                bf16x4 kf = *(const bf16x4*)(lK + krow * DH + sb * 8 + (g & 1) * 4);
                acc = MFMA16(kf, qf[f], acc);
            }
            st[kg] = acc;
        }
        float tm = -1e30f;
#pragma unroll
        for (int kg = 0; kg < 4; kg++)
#pragma unroll
            for (int rr = 0; rr < 4; rr++){
                float s = st[kg][rr] * scale;
                if (mrow[key0 + kg * 16 + g * 4 + rr]) s = -1e30f;
                st[kg][rr] = s;
                tm = fmaxf(tm, s);
            }
        tm = fmaxf(tm, __shfl_xor(tm, 16));
        tm = fmaxf(tm, __shfl_xor(tm, 32));
        float mnew = fmaxf(m, tm);
        float fac = __expf(m - mnew);
        float rs = 0.f;
        bf16x4 pa[4];
#pragma unroll
        for (int kg = 0; kg < 4; kg++)
#pragma unroll
            for (int rr = 0; rr < 4; rr++){
                float p = __expf(st[kg][rr] - mnew);
                rs += p;
                pa[kg][rr] = f2bf(p);
            }
        rs += __shfl_xor(rs, 16);
        rs += __shfl_xor(rs, 32);
        ssum = ssum * fac + rs;
        m = mnew;
        float fr[4];
#pragma unroll
        for (int rr = 0; rr < 4; rr++) fr[rr] = __shfl(fac, g * 4 + rr);
#pragma unroll
        for (int dvc = 0; dvc < 4; dvc++){
            f32x4 o = oacc[dvc];
#pragma unroll
            for (int rr = 0; rr < 4; rr++) o[rr] *= fr[rr];
            int vrow = dvc * 16 + cl;
#pragma unroll
            for (int kg = 0; kg < 4; kg++){
                int sb = (2 * kg + (g >> 1)) ^ (vrow & 7);
                bf16x4 vf = *(const bf16x4*)(lV + vrow * KT + sb * 8 + (g & 1) * 4);
                o = MFMA16(pa[kg], vf, o);
            }
            oacc[dvc] = o;
        }
    }
    float linv[4];
#pragma unroll
    for (int rr = 0; rr < 4; rr++) linv[rr] = 1.f / __shfl(ssum, g * 4 + rr);
#pragma unroll
    for (int dvc = 0; dvc < 4; dvc++)
#pragma unroll
        for (int rr = 0; rr < 4; rr++){
            int q = q0 + g * 4 + rr;
            out[(((long)b * Qn + q) * H + h) * DV + dvc * 16 + cl] = oacc[dvc][rr] * linv[rr];
        }
}

// ================= host orchestration =================
extern "C" void kernel_launch(void* const* d_in, const int* in_sizes, int n_in,
                              void* d_out, int out_size, void* d_ws, size_t ws_size,
                              hipStream_t stream)
{
    (void)in_sizes; (void)n_in; (void)out_size; (void)ws_size;
    const int B = 8, Qn = 1024, Kn = 2048, H = 8;
    const long MQ = (long)B * Qn;   // 8192
    const long MK = (long)B * Kn;   // 16384

    const float* queries = (const float*)d_in[0];
    const unsigned char* qmask = (const unsigned char*)d_in[1];
    const float* box  = (const float*)d_in[2];
    const float* ctr  = (const float*)d_in[3];
    const float* kvd  = (const float*)d_in[4];
    const unsigned char* kmask = (const unsigned char*)d_in[5];
    const float* kvp  = (const float*)d_in[6];
    const float* w_qkv = (const float*)d_in[7];  const float* b_qkv = (const float*)d_in[8];
    const float* w_pos = (const float*)d_in[9];  const float* b_pos = (const float*)d_in[10];
    const float* g_sa  = (const float*)d_in[11]; const float* be_sa = (const float*)d_in[12];
    const float* w_caq = (const float*)d_in[13]; const float* b_caq = (const float*)d_in[14];
    const float* w_cakv = (const float*)d_in[15]; const float* b_cakv = (const float*)d_in[16];
    const float* w_caqp = (const float*)d_in[17]; const float* b_caqp = (const float*)d_in[18];
    const float* w_cakp = (const float*)d_in[19]; const float* b_cakp = (const float*)d_in[20];
    const float* g_ca  = (const float*)d_in[21]; const float* be_ca = (const float*)d_in[22];
    const float* w_f1  = (const float*)d_in[23]; const float* b_f1 = (const float*)d_in[24];
    const float* w_f2  = (const float*)d_in[25]; const float* b_f2 = (const float*)d_in[26];
    const float* g_f   = (const float*)d_in[27]; const float* be_f = (const float*)d_in[28];

    char* ws = (char*)d_ws;
    size_t off = 0;
    auto alloc = [&](size_t bytes) -> char* {
        char* p = ws + off;
        off += (bytes + 255) & ~(size_t)255;
        return p;
    };
    // persistent
    short* wT_qkv  = (short*)alloc(1536L * 512 * 2);
    short* wT_pos  = (short*)alloc(1024L * 1024 * 2);
    short* wT_caq  = (short*)alloc(512L * 512 * 2);
    short* wT_cakv = (short*)alloc(1024L * 256 * 2);
    short* wT_caqp = (short*)alloc(512L * 512 * 2);
    short* wT_cakp = (short*)alloc(512L * 256 * 2);
    short* wT_f1   = (short*)alloc(2048L * 512 * 2);
    short* wT_f2   = (short*)alloc(512L * 2048 * 2);
    short* ctr_bf  = (short*)alloc(MQ * 512 * 2);
    short* kvd_bf  = (short*)alloc(MK * 256 * 2);
    short* kvp_bf  = (short*)alloc(MK * 256 * 2);
    short* saln_bf = (short*)alloc(MQ * 512 * 2);
    short* caln_bf = (short*)alloc(MQ * 512 * 2);
    float* sa_ln_f = (float*)alloc(MQ * 512 * 4);
    float* ca_ln_f = (float*)alloc(MQ * 512 * 4);
    float* att_f   = (float*)alloc(MQ * 512 * 4);        // shared by SA and CA attention outs
    float* f_out   = (float*)alloc(MQ * 512 * 4);
    short* VtSA    = (short*)alloc(64L * 64 * 1024 * 2);
    short* VtCA    = (short*)alloc(64L * 64 * 2048 * 2);
    // overlay zones (lifetimes verified phase-by-phase)
    char* zoneA = alloc(MQ * 1536 * 2);          // qkv_bf | cakv_bf
    char* zoneB = alloc(MQ * 1024 * 2);          // pos_bf | cakp_bf
    char* zoneC = alloc(MQ * 512 * 2);           // xq_bf | caq_bf
    char* zoneD = alloc(MQ * 1024 * 2);          // box_bf | Qcat
    char* zoneE = alloc(MQ * 512 * 2);           // Qa | caqp_bf
    char* zoneF = alloc(MQ * 512 * 2);           // Ka
    char* zoneG = alloc(64L * 2048 * 128 * 2);   // Kcat | mid_bf

    auto cast = [&](const float* src, short* dst, long n){
        cast_f32_bf16<<<dim3((unsigned)(n / 8 / 256)), dim3(256), 0, stream>>>(src, dst, n);
    };
    auto trans = [&](const float* wsrc, short* wT, int K, int N){
        transcast<<<dim3(N / 256, K / 8), dim3(256), 0, stream>>>(wsrc, wT, K, N);
    };
    auto gemm = [&](const short* A, const short* Bt, const float* bias, short* Cbf, float* Cf,
                    int M, int N, int K, int relu){
        gemm_bf16<<<dim3(N / 128, M / 128), dim3(256), 0, stream>>>(A, Bt, bias, Cbf, Cf, M, N, K, relu);
    };

    // P0: casts + weight transposes
    short* xq_bf  = (short*)zoneC;
    short* box_bf = (short*)zoneD;
    cast(queries, xq_bf, MQ * 512);
    cast(box, box_bf, MQ * 1024);
    cast(ctr, ctr_bf, MQ * 512);
    cast(kvd, kvd_bf, MK * 256);
    cast(kvp, kvp_bf, MK * 256);
    trans(w_qkv, wT_qkv, 512, 1536);
    trans(w_pos, wT_pos, 1024, 1024);
    trans(w_caq, wT_caq, 512, 512);
    trans(w_cakv, wT_cakv, 256, 1024);
    trans(w_caqp, wT_caqp, 512, 512);
    trans(w_cakp, wT_cakp, 256, 512);
    trans(w_f1, wT_f1, 512, 2048);
    trans(w_f2, wT_f2, 2048, 512);

    // P1-P2: SA projections
    short* qkv_bf = (short*)zoneA;
    short* pos_bf = (short*)zoneB;
    gemm(xq_bf, wT_qkv, b_qkv, qkv_bf, nullptr, (int)MQ, 1536, 512, 0);
    gemm(box_bf, wT_pos, b_pos, pos_bf, nullptr, (int)MQ, 1024, 1024, 0);

    // P3: SA fuse
    short* Qa = (short*)zoneE;
    short* Ka = (short*)zoneF;
    fuse_sa_qk<<<dim3(2048), dim3(256), 0, stream>>>(qkv_bf, pos_bf, Qa, Ka);
    fuse_vt<<<dim3(Qn / 32, 64), dim3(256), 0, stream>>>(qkv_bf, VtSA, 1536, 1024, Qn);

    // P4: SA attention
    attn_kernel<64, 1024><<<dim3(Qn / 64, 64), dim3(256), 0, stream>>>(
        Qa, Ka, VtSA, qmask, att_f, 0.125f);

    // P5: LN1
    ln_fuse<<<dim3((unsigned)(MQ / 4)), dim3(256), 0, stream>>>(queries, att_f, g_sa, be_sa, sa_ln_f, saln_bf);

    // P6-P8: CA query path
    short* caq_bf  = (short*)zoneC;
    short* caqp_bf = (short*)zoneE;
    gemm(saln_bf, wT_caq, b_caq, caq_bf, nullptr, (int)MQ, 512, 512, 0);
    gemm(ctr_bf, wT_caqp, b_caqp, caqp_bf, nullptr, (int)MQ, 512, 512, 0);
    short* Qcat = (short*)zoneD;
    fuse_cat<<<dim3(4096), dim3(256), 0, stream>>>(caq_bf, caqp_bf, Qcat, 1024, 10, 512, 512);

    // P9-P11: CA key/value path
    short* cakv_bf = (short*)zoneA;
    short* cakp_bf = (short*)zoneB;
    gemm(kvd_bf, wT_cakv, b_cakv, cakv_bf, nullptr, (int)MK, 1024, 256, 0);
    gemm(kvp_bf, wT_cakp, b_cakp, cakp_bf, nullptr, (int)MK, 512, 256, 0);
    short* Kcat = (short*)zoneG;
    fuse_cat<<<dim3(8192), dim3(256), 0, stream>>>(cakv_bf, cakp_bf, Kcat, 2048, 11, 1024, 512);
    fuse_vt<<<dim3(Kn / 32, 64), dim3(256), 0, stream>>>(cakv_bf, VtCA, 1024, 512, Kn);

    // P12: CA attention
    attn_kernel<128, 2048><<<dim3(Qn / 64, 64), dim3(256), 0, stream>>>(
        Qcat, Kcat, VtCA, kmask, att_f, 0.08838834764831845f);

    // P13: LN2
    ln_fuse<<<dim3((unsigned)(MQ / 4)), dim3(256), 0, stream>>>(sa_ln_f, att_f, g_ca, be_ca, ca_ln_f, caln_bf);

    // P14-P15: FFN
    short* mid_bf = (short*)zoneG;
    gemm(caln_bf, wT_f1, b_f1, mid_bf, nullptr, (int)MQ, 2048, 512, 1);
    gemm(mid_bf, wT_f2, b_f2, nullptr, f_out, (int)MQ, 512, 2048, 0);

    // P16: final LN -> d_out
    ln_fuse<<<dim3((unsigned)(MQ / 4)), dim3(256), 0, stream>>>(ca_ln_f, f_out, g_f, be_f, (float*)d_out, (short*)nullptr);
}

// Round 3
// 446.888 us; speedup vs baseline: 1.1171x; 1.1171x over previous
//
#include <hip/hip_runtime.h>

typedef __attribute__((ext_vector_type(4))) float f32x4;
typedef __attribute__((ext_vector_type(8))) short bf16x8;
typedef __attribute__((ext_vector_type(4))) short bf16x4;
typedef __attribute__((ext_vector_type(4))) unsigned int u32x4;

static __device__ __forceinline__ float bf2f(short s){
    unsigned int u = ((unsigned int)(unsigned short)s) << 16;
    return __builtin_bit_cast(float, u);
}
static __device__ __forceinline__ short f2bf(float f){
    unsigned int u = __builtin_bit_cast(unsigned int, f);
    unsigned int r = (u + 0x7fffu + ((u >> 16) & 1u)) >> 16;
    return (short)r;
}
static __device__ __forceinline__ void gload_lds16(const void* g, void* l){
    __builtin_amdgcn_global_load_lds((const __attribute__((address_space(1))) void*)g,
                                     (__attribute__((address_space(3))) void*)l, 16, 0, 0);
}
// exp2 via raw v_exp_f32 (single TRANS op; log2-domain softmax)
static __device__ __forceinline__ float exp2fast(float x){
    float r; asm("v_exp_f32 %0, %1" : "=v"(r) : "v"(x)); return r;
}
// pack two f32 -> bf16x2 (truncation) in one v_perm_b32
static __device__ __forceinline__ unsigned int packbf(float lo, float hi){
#if __has_builtin(__builtin_amdgcn_perm)
    return __builtin_amdgcn_perm(__builtin_bit_cast(unsigned int, hi),
                                 __builtin_bit_cast(unsigned int, lo), 0x07060302u);
#else
    return (__builtin_bit_cast(unsigned int, hi) & 0xffff0000u) |
           (__builtin_bit_cast(unsigned int, lo) >> 16);
#endif
}

// ---------------- elementwise cast fp32 -> bf16 ----------------
__global__ __launch_bounds__(256) void cast_f32_bf16(const float* __restrict__ in,
                                                     short* __restrict__ out, long n){
    long i = ((long)blockIdx.x * 256 + threadIdx.x) * 8;
    if (i >= n) return;
    f32x4 a = *(const f32x4*)(in + i);
    f32x4 b = *(const f32x4*)(in + i + 4);
    bf16x8 o;
#pragma unroll
    for (int j = 0; j < 4; j++){ o[j] = f2bf(a[j]); o[4 + j] = f2bf(b[j]); }
    *(bf16x8*)(out + i) = o;
}

// ---------------- mask byte -> additive bias (0 / -1e30) ----------------
__global__ __launch_bounds__(256) void build_mbias(const unsigned char* __restrict__ m,
                                                   float* __restrict__ o, int n){
    int i = blockIdx.x * 256 + threadIdx.x;
    if (i < n) o[i] = m[i] ? -1e30f : 0.f;
}

// ---------------- weight transpose-cast: w[K][N] -> wT[N][K] bf16 ----------------
__global__ __launch_bounds__(256) void transcast(const float* __restrict__ w,
                                                 short* __restrict__ wT, int K, int N){
    int n = blockIdx.x * 256 + threadIdx.x;
    int k0 = blockIdx.y * 8;
    bf16x8 o;
#pragma unroll
    for (int j = 0; j < 8; j++) o[j] = f2bf(w[(long)(k0 + j) * N + n]);
    *(bf16x8*)(wT + (long)n * K + k0) = o;
}

// ---------------- GEMM: C[M,N] = A[M,K](bf16) @ Bt[N,K]^T(bf16) + bias ----------------
__global__ __launch_bounds__(256, 2) void gemm_bf16(
    const short* __restrict__ A, const short* __restrict__ Bt, const float* __restrict__ bias,
    short* __restrict__ Cbf, float* __restrict__ Cf, int M, int N, int K, int doRelu)
{
    __shared__ __attribute__((aligned(16))) short lA[128 * 32];
    __shared__ __attribute__((aligned(16))) short lB[128 * 32];
    int t = threadIdx.x, w = t >> 6, l = t & 63;
    int cl = l & 15, g = l >> 4;
    long r0 = (long)blockIdx.y * 128, c0 = (long)blockIdx.x * 128;
    int wr = w >> 1, wc = w & 1;
    f32x4 acc[4][4];
#pragma unroll
    for (int mi = 0; mi < 4; mi++)
#pragma unroll
        for (int ni = 0; ni < 4; ni++) acc[mi][ni] = f32x4{0.f, 0.f, 0.f, 0.f};
    int srow = t >> 2, sblk = t & 3;
    for (int k0 = 0; k0 < K; k0 += 32){
        __syncthreads();
#pragma unroll
        for (int i = 0; i < 2; i++){
            int rrow = srow + i * 64;
            int sb = sblk ^ (rrow & 3);
            gload_lds16(A + (r0 + rrow) * (long)K + k0 + sb * 8, (char*)lA + i * 4096 + w * 1024);
            gload_lds16(Bt + (c0 + rrow) * (long)K + k0 + sb * 8, (char*)lB + i * 4096 + w * 1024);
        }
        __syncthreads();
        bf16x8 af[4], bfr[4];
#pragma unroll
        for (int mi = 0; mi < 4; mi++){
            int row = wr * 64 + mi * 16 + cl;
            af[mi] = *(const bf16x8*)(lA + row * 32 + (g ^ (row & 3)) * 8);
        }
#pragma unroll
        for (int ni = 0; ni < 4; ni++){
            int row = wc * 64 + ni * 16 + cl;
            bfr[ni] = *(const bf16x8*)(lB + row * 32 + (g ^ (row & 3)) * 8);
        }
#pragma unroll
        for (int mi = 0; mi < 4; mi++)
#pragma unroll
            for (int ni = 0; ni < 4; ni++)
                acc[mi][ni] = __builtin_amdgcn_mfma_f32_16x16x32_bf16(af[mi], bfr[ni], acc[mi][ni], 0, 0, 0);
    }
#pragma unroll
    for (int mi = 0; mi < 4; mi++)
#pragma unroll
        for (int ni = 0; ni < 4; ni++){
            long col = c0 + wc * 64 + ni * 16 + cl;
            float bv = bias[col];
#pragma unroll
            for (int rr = 0; rr < 4; rr++){
                long rowg = r0 + wr * 64 + mi * 16 + g * 4 + rr;
                float v = acc[mi][ni][rr] + bv;
                if (doRelu) v = fmaxf(v, 0.f);
                long idx = rowg * N + col;
                if (Cbf) Cbf[idx] = f2bf(v);
                if (Cf)  Cf[idx]  = v;
            }
        }
}

// ---------------- SA fuse: Qa/Ka = (qkv q/k) + (pos q/k), head-split [bh][qn][64] ----------------
__global__ __launch_bounds__(256) void fuse_sa_qk(const short* __restrict__ qkv,
                                                  const short* __restrict__ pos,
                                                  short* __restrict__ Qa, short* __restrict__ Ka){
    long i = (long)blockIdx.x * 256 + threadIdx.x;
    long row = i >> 6;
    int c = (int)(i & 63) * 8;
    int h = c >> 6, d = c & 63;
    long b = row >> 10, qn = row & 1023;
    long obase = ((b * 8 + h) * 1024 + qn) * 64 + d;
    bf16x8 q  = *(const bf16x8*)(qkv + row * 1536 + c);
    bf16x8 k  = *(const bf16x8*)(qkv + row * 1536 + 512 + c);
    bf16x8 qp = *(const bf16x8*)(pos + row * 1024 + c);
    bf16x8 kp = *(const bf16x8*)(pos + row * 1024 + 512 + c);
    bf16x8 oq, ok;
#pragma unroll
    for (int j = 0; j < 8; j++){
        oq[j] = f2bf(bf2f(q[j]) + bf2f(qp[j]));
        ok[j] = f2bf(bf2f(k[j]) + bf2f(kp[j]));
    }
    *(bf16x8*)(Qa + obase) = oq;
    *(bf16x8*)(Ka + obase) = ok;
}

// ---------------- V transpose: Vt[bh][dv=64][KN] ----------------
__global__ __launch_bounds__(256) void fuse_vt(const short* __restrict__ src, short* __restrict__ Vt,
                                               int srcStride, int colBase, int KN){
    long bh = blockIdx.y; long b = bh >> 3; int h = (int)bh & 7;
    int dv = threadIdx.x & 63;
    int kn0 = blockIdx.x * 32 + (threadIdx.x >> 6) * 8;
    long base = (b * (long)KN + kn0) * srcStride + colBase + h * 64 + dv;
    bf16x8 o;
#pragma unroll
    for (int j = 0; j < 8; j++) o[j] = src[base + (long)j * srcStride];
    *(bf16x8*)(Vt + (bh * 64 + dv) * (long)KN + kn0) = o;
}

// ---------------- per-head concat: out[bh][n][128] = [a_head(64) | p_head(64)] ----------------
__global__ __launch_bounds__(256) void fuse_cat(const short* __restrict__ abuf,
                                                const short* __restrict__ pbuf,
                                                short* __restrict__ out,
                                                int SN, int snShift, int aStride, int pStride){
    long i = (long)blockIdx.x * 256 + threadIdx.x;
    long bh = i >> (4 + snShift);
    long n = (i >> 4) & (SN - 1);
    int c = ((int)i & 15) * 8;
    long b = bh >> 3; int h = (int)bh & 7;
    const short* s = (c < 64) ? (abuf + (b * SN + n) * (long)aStride + h * 64 + c)
                              : (pbuf + (b * SN + n) * (long)pStride + h * 64 + (c - 64));
    *(bf16x8*)(out + i * 8) = *(const bf16x8*)s;
}

// ---------------- fused residual + LayerNorm (512 cols), wave-per-row ----------------
__global__ __launch_bounds__(256) void ln_fuse(const float* __restrict__ a, const float* __restrict__ b,
                                               const float* __restrict__ g, const float* __restrict__ be,
                                               float* __restrict__ outf, short* __restrict__ outb){
    int w = threadIdx.x >> 6, l = threadIdx.x & 63;
    long row = (long)blockIdx.x * 4 + w;
    long base = row * 512 + l * 8;
    f32x4 a0 = *(const f32x4*)(a + base);
    f32x4 a1 = *(const f32x4*)(a + base + 4);
    f32x4 b0 = *(const f32x4*)(b + base);
    f32x4 b1 = *(const f32x4*)(b + base + 4);
    float x[8]; float s = 0.f, s2 = 0.f;
#pragma unroll
    for (int j = 0; j < 4; j++){ x[j] = a0[j] + b0[j]; x[4 + j] = a1[j] + b1[j]; }
#pragma unroll
    for (int j = 0; j < 8; j++){ s += x[j]; s2 += x[j] * x[j]; }
#pragma unroll
    for (int o = 1; o < 64; o <<= 1){ s += __shfl_xor(s, o); s2 += __shfl_xor(s2, o); }
    float mean = s * (1.f / 512.f);
    float rstd = rsqrtf(s2 * (1.f / 512.f) - mean * mean + 1e-5f);
    int c = l * 8;
    f32x4 y0, y1; bf16x8 ob;
#pragma unroll
    for (int j = 0; j < 4; j++){
        float y = (x[j] - mean) * rstd * g[c + j] + be[c + j];
        y0[j] = y; ob[j] = f2bf(y);
    }
#pragma unroll
    for (int j = 0; j < 4; j++){
        float y = (x[4 + j] - mean) * rstd * g[c + 4 + j] + be[c + 4 + j];
        y1[j] = y; ob[4 + j] = f2bf(y);
    }
    *(f32x4*)(outf + base) = y0;
    *(f32x4*)(outf + base + 4) = y1;
    if (outb) *(bf16x8*)(outb + base) = ob;
}

// ---------------- flash attention (mfma32, permuted keys, log2 softmax) ----------------
// Q[bh][Qn][DH], K[bh][KN][DH], Vt[bh][64][KN] bf16; mbias[b][KN] f32; out[b][q][h*64+dv] f32.
// 4 waves/block, each wave owns 32 q-rows (2 groups of 16); block = 128 q-rows.
// K LDS rows hold keys in permuted order: slot 16h+4g+rr <- key 8g+4h+rr (per 32-group),
// so the QK^T C-layout coincides exactly with the PV mfma32 A-fragment (keys 8g..8g+7).
// 16B-block XOR swizzle on both tiles (pre-swizzled global source, same XOR on read).
template<int DH, int KN>
__global__ __launch_bounds__(256, 2) void attn_kernel(
    const short* __restrict__ Q, const short* __restrict__ K, const short* __restrict__ Vt,
    const float* __restrict__ mbias, float* __restrict__ out, float scale2)
{
    constexpr int KT = 64, DV = 64, Qn = 1024, H = 8;
    constexpr int NF = DH / 32;            // mfma k-steps over DH (4 or 2)
    constexpr int BPR = DH / 8;            // 16B blocks per K row (16 or 8)
    constexpr int KITER = KT * BPR / 256;  // K staging iters (4 or 2)
    __shared__ __attribute__((aligned(16))) short lK[KT * DH];
    __shared__ __attribute__((aligned(16))) short lV[DV * KT];
    int t = threadIdx.x, w = t >> 6, l = t & 63;
    int cl = l & 15, g = l >> 4;
    // XCD-aware bijective swizzle: 512 blocks, 8 XCDs, each XCD owns 8 consecutive bh
    int bid = blockIdx.x;
    int bh = (bid & 7) * 8 + (bid >> 6);
    int qb = (bid >> 3) & 7;
    int b = bh >> 3, h = bh & 7;
    int q0 = qb * 128 + w * 32;

    bf16x8 qf[2][NF];
    {
        const short* qbase = Q + (long)bh * Qn * DH;
#pragma unroll
        for (int qq = 0; qq < 2; qq++)
#pragma unroll
            for (int f = 0; f < NF; f++)
                qf[qq][f] = *(const bf16x8*)(qbase + (long)(q0 + qq * 16 + cl) * DH + f * 32 + 8 * g);
    }
    const float* mrow = mbias + (long)b * KN;
    float m[2] = {-1e30f, -1e30f}, ssum[2] = {0.f, 0.f};
    f32x4 oacc[2][4];
#pragma unroll
    for (int qq = 0; qq < 2; qq++)
#pragma unroll
        for (int d = 0; d < 4; d++) oacc[qq][d] = f32x4{0.f, 0.f, 0.f, 0.f};

    for (int key0 = 0; key0 < KN; key0 += KT){
        __syncthreads();
        // stage K (permuted key rows, swizzled 16B blocks)
#pragma unroll
        for (int i = 0; i < KITER; i++){
            int s = i * 256 + t;
            int srow = s / BPR, blk = s % BPR;
            int s32 = srow & 31;
            int key = (srow & 32) + 8 * ((s32 >> 2) & 3) + 4 * (s32 >> 4) + (s32 & 3);
            int sb = blk ^ (srow & 7);
            gload_lds16(K + ((long)bh * KN + key0 + key) * DH + sb * 8, (char*)lK + i * 4096 + w * 1024);
        }
        // stage V^T (natural key order, swizzled)
#pragma unroll
        for (int i = 0; i < 2; i++){
            int s = i * 256 + t;
            int row = s >> 3, blk = s & 7;
            int sb = blk ^ (row & 7);
            gload_lds16(Vt + ((long)bh * DV + row) * KN + key0 + sb * 8, (char*)lV + i * 4096 + w * 1024);
        }
        __syncthreads();

        // QK^T: 4 outputs (16 key-slots each) x 2 q-groups
        f32x4 st[2][4];
#pragma unroll
        for (int o = 0; o < 4; o++){
            bf16x8 kf[NF];
            int srow = o * 16 + cl;
#pragma unroll
            for (int f = 0; f < NF; f++){
                int sb = (4 * f + g) ^ (srow & 7);
                kf[f] = *(const bf16x8*)(lK + srow * DH + sb * 8);
            }
#pragma unroll
            for (int qq = 0; qq < 2; qq++){
                f32x4 acc = f32x4{0.f, 0.f, 0.f, 0.f};
#pragma unroll
                for (int f = 0; f < NF; f++)
                    acc = __builtin_amdgcn_mfma_f32_16x16x32_bf16(kf[f], qf[qq][f], acc, 0, 0, 0);
                st[qq][o] = acc;
            }
        }
        // mask bias (shared across q-groups); lane's key for (o,rr): (o>>1)*32 + 8g + 4*(o&1) + rr
        f32x4 mb[4];
#pragma unroll
        for (int o = 0; o < 4; o++)
            mb[o] = *(const f32x4*)(mrow + key0 + (o >> 1) * 32 + 8 * g + 4 * (o & 1));

        bf16x8 pa[2][2];
        float fr[2][4];
#pragma unroll
        for (int qq = 0; qq < 2; qq++){
            f32x4 s2[4];
            float tm = -1e30f;
#pragma unroll
            for (int o = 0; o < 4; o++){
#pragma unroll
                for (int rr = 0; rr < 4; rr++)
                    s2[o][rr] = fmaf(st[qq][o][rr], scale2, mb[o][rr]);
                tm = fmaxf(tm, fmaxf(fmaxf(s2[o][0], s2[o][1]), fmaxf(s2[o][2], s2[o][3])));
            }
            tm = fmaxf(tm, __shfl_xor(tm, 16));
            tm = fmaxf(tm, __shfl_xor(tm, 32));
            float mnew = fmaxf(m[qq], tm);
            float fac = exp2fast(m[qq] - mnew);
            float rs = 0.f;
#pragma unroll
            for (int kb = 0; kb < 2; kb++){
                float pA[4], pB[4];
#pragma unroll
                for (int rr = 0; rr < 4; rr++){
                    pA[rr] = exp2fast(s2[2 * kb][rr] - mnew);
                    pB[rr] = exp2fast(s2[2 * kb + 1][rr] - mnew);
                    rs += pA[rr] + pB[rr];
                }
                u32x4 pk;
                pk[0] = packbf(pA[0], pA[1]);
                pk[1] = packbf(pA[2], pA[3]);
                pk[2] = packbf(pB[0], pB[1]);
                pk[3] = packbf(pB[2], pB[3]);
                pa[qq][kb] = __builtin_bit_cast(bf16x8, pk);
            }
            rs += __shfl_xor(rs, 16);
            rs += __shfl_xor(rs, 32);
            ssum[qq] = ssum[qq] * fac + rs;
            m[qq] = mnew;
#pragma unroll
            for (int rr = 0; rr < 4; rr++) fr[qq][rr] = __shfl(fac, 4 * g + rr);
        }
        // PV: O += P * V   (V B-frag: lane needs V[key=kb*32+8g+j][dv=dvc*16+cl])
#pragma unroll
        for (int dvc = 0; dvc < 4; dvc++){
            int vrow = dvc * 16 + cl;
            bf16x8 vf[2];
#pragma unroll
            for (int kb = 0; kb < 2; kb++){
                int sb = (4 * kb + g) ^ (vrow & 7);
                vf[kb] = *(const bf16x8*)(lV + vrow * KT + sb * 8);
            }
#pragma unroll
            for (int qq = 0; qq < 2; qq++){
                f32x4 o = oacc[qq][dvc];
#pragma unroll
                for (int rr = 0; rr < 4; rr++) o[rr] *= fr[qq][rr];
                o = __builtin_amdgcn_mfma_f32_16x16x32_bf16(pa[qq][0], vf[0], o, 0, 0, 0);
                o = __builtin_amdgcn_mfma_f32_16x16x32_bf16(pa[qq][1], vf[1], o, 0, 0, 0);
                oacc[qq][dvc] = o;
            }
        }
    }
#pragma unroll
    for (int qq = 0; qq < 2; qq++){
        float linv[4];
#pragma unroll
        for (int rr = 0; rr < 4; rr++) linv[rr] = 1.f / __shfl(ssum[qq], 4 * g + rr);
#pragma unroll
        for (int dvc = 0; dvc < 4; dvc++)
#pragma unroll
            for (int rr = 0; rr < 4; rr++){
                int q = q0 + qq * 16 + 4 * g + rr;
                out[(((long)b * Qn + q) * H + h) * DV + dvc * 16 + cl] = oacc[qq][dvc][rr] * linv[rr];
            }
    }
}

// ================= host orchestration =================
extern "C" void kernel_launch(void* const* d_in, const int* in_sizes, int n_in,
                              void* d_out, int out_size, void* d_ws, size_t ws_size,
                              hipStream_t stream)
{
    (void)in_sizes; (void)n_in; (void)out_size; (void)ws_size;
    const int Qn = 1024, Kn = 2048;
    const long MQ = 8L * Qn;   // 8192
    const long MK = 8L * Kn;   // 16384

    const float* queries = (const float*)d_in[0];
    const unsigned char* qmask = (const unsigned char*)d_in[1];
    const float* box  = (const float*)d_in[2];
    const float* ctr  = (const float*)d_in[3];
    const float* kvd  = (const float*)d_in[4];
    const unsigned char* kmask = (const unsigned char*)d_in[5];
    const float* kvp  = (const float*)d_in[6];
    const float* w_qkv = (const float*)d_in[7];  const float* b_qkv = (const float*)d_in[8];
    const float* w_pos = (const float*)d_in[9];  const float* b_pos = (const float*)d_in[10];
    const float* g_sa  = (const float*)d_in[11]; const float* be_sa = (const float*)d_in[12];
    const float* w_caq = (const float*)d_in[13]; const float* b_caq = (const float*)d_in[14];
    const float* w_cakv = (const float*)d_in[15]; const float* b_cakv = (const float*)d_in[16];
    const float* w_caqp = (const float*)d_in[17]; const float* b_caqp = (const float*)d_in[18];
    const float* w_cakp = (const float*)d_in[19]; const float* b_cakp = (const float*)d_in[20];
    const float* g_ca  = (const float*)d_in[21]; const float* be_ca = (const float*)d_in[22];
    const float* w_f1  = (const float*)d_in[23]; const float* b_f1 = (const float*)d_in[24];
    const float* w_f2  = (const float*)d_in[25]; const float* b_f2 = (const float*)d_in[26];
    const float* g_f   = (const float*)d_in[27]; const float* be_f = (const float*)d_in[28];

    char* ws = (char*)d_ws;
    size_t off = 0;
    auto alloc = [&](size_t bytes) -> char* {
        char* p = ws + off;
        off += (bytes + 255) & ~(size_t)255;
        return p;
    };
    short* wT_qkv  = (short*)alloc(1536L * 512 * 2);
    short* wT_pos  = (short*)alloc(1024L * 1024 * 2);
    short* wT_caq  = (short*)alloc(512L * 512 * 2);
    short* wT_cakv = (short*)alloc(1024L * 256 * 2);
    short* wT_caqp = (short*)alloc(512L * 512 * 2);
    short* wT_cakp = (short*)alloc(512L * 256 * 2);
    short* wT_f1   = (short*)alloc(2048L * 512 * 2);
    short* wT_f2   = (short*)alloc(512L * 2048 * 2);
    short* ctr_bf  = (short*)alloc(MQ * 512 * 2);
    short* kvd_bf  = (short*)alloc(MK * 256 * 2);
    short* kvp_bf  = (short*)alloc(MK * 256 * 2);
    short* saln_bf = (short*)alloc(MQ * 512 * 2);
    short* caln_bf = (short*)alloc(MQ * 512 * 2);
    float* sa_ln_f = (float*)alloc(MQ * 512 * 4);
    float* ca_ln_f = (float*)alloc(MQ * 512 * 4);
    float* att_f   = (float*)alloc(MQ * 512 * 4);
    float* f_out   = (float*)alloc(MQ * 512 * 4);
    short* VtSA    = (short*)alloc(64L * 64 * 1024 * 2);
    short* VtCA    = (short*)alloc(64L * 64 * 2048 * 2);
    float* mb_sa   = (float*)alloc(MQ * 4);
    float* mb_ca   = (float*)alloc(MK * 4);
    char* zoneA = alloc(MQ * 1536 * 2);          // qkv_bf | cakv_bf
    char* zoneB = alloc(MQ * 1024 * 2);          // pos_bf | cakp_bf
    char* zoneC = alloc(MQ * 512 * 2);           // xq_bf | caq_bf
    char* zoneD = alloc(MQ * 1024 * 2);          // box_bf | Qcat
    char* zoneE = alloc(MQ * 512 * 2);           // Qa | caqp_bf
    char* zoneF = alloc(MQ * 512 * 2);           // Ka
    char* zoneG = alloc(64L * 2048 * 128 * 2);   // Kcat | mid_bf

    auto cast = [&](const float* src, short* dst, long n){
        cast_f32_bf16<<<dim3((unsigned)(n / 8 / 256)), dim3(256), 0, stream>>>(src, dst, n);
    };
    auto trans = [&](const float* wsrc, short* wT, int K, int N){
        transcast<<<dim3(N / 256, K / 8), dim3(256), 0, stream>>>(wsrc, wT, K, N);
    };
    auto gemm = [&](const short* A, const short* Bt, const float* bias, short* Cbf, float* Cf,
                    int M, int N, int K, int relu){
        gemm_bf16<<<dim3(N / 128, M / 128), dim3(256), 0, stream>>>(A, Bt, bias, Cbf, Cf, M, N, K, relu);
    };

    // P0: casts + weight transposes + mask bias
    short* xq_bf  = (short*)zoneC;
    short* box_bf = (short*)zoneD;
    cast(queries, xq_bf, MQ * 512);
    cast(box, box_bf, MQ * 1024);
    cast(ctr, ctr_bf, MQ * 512);
    cast(kvd, kvd_bf, MK * 256);
    cast(kvp, kvp_bf, MK * 256);
    build_mbias<<<dim3(32), dim3(256), 0, stream>>>(qmask, mb_sa, (int)MQ);
    build_mbias<<<dim3(64), dim3(256), 0, stream>>>(kmask, mb_ca, (int)MK);
    trans(w_qkv, wT_qkv, 512, 1536);
    trans(w_pos, wT_pos, 1024, 1024);
    trans(w_caq, wT_caq, 512, 512);
    trans(w_cakv, wT_cakv, 256, 1024);
    trans(w_caqp, wT_caqp, 512, 512);
    trans(w_cakp, wT_cakp, 256, 512);
    trans(w_f1, wT_f1, 512, 2048);
    trans(w_f2, wT_f2, 2048, 512);

    // P1-P2: SA projections
    short* qkv_bf = (short*)zoneA;
    short* pos_bf = (short*)zoneB;
    gemm(xq_bf, wT_qkv, b_qkv, qkv_bf, nullptr, (int)MQ, 1536, 512, 0);
    gemm(box_bf, wT_pos, b_pos, pos_bf, nullptr, (int)MQ, 1024, 1024, 0);

    // P3: SA fuse
    short* Qa = (short*)zoneE;
    short* Ka = (short*)zoneF;
    fuse_sa_qk<<<dim3(2048), dim3(256), 0, stream>>>(qkv_bf, pos_bf, Qa, Ka);
    fuse_vt<<<dim3(Qn / 32, 64), dim3(256), 0, stream>>>(qkv_bf, VtSA, 1536, 1024, Qn);

    // P4: SA attention
    attn_kernel<64, 1024><<<dim3(512), dim3(256), 0, stream>>>(
        Qa, Ka, VtSA, mb_sa, att_f, 0.125f * 1.44269504f);

    // P5: LN1
    ln_fuse<<<dim3((unsigned)(MQ / 4)), dim3(256), 0, stream>>>(queries, att_f, g_sa, be_sa, sa_ln_f, saln_bf);

    // P6-P8: CA query path
    short* caq_bf  = (short*)zoneC;
    short* caqp_bf = (short*)zoneE;
    gemm(saln_bf, wT_caq, b_caq, caq_bf, nullptr, (int)MQ, 512, 512, 0);
    gemm(ctr_bf, wT_caqp, b_caqp, caqp_bf, nullptr, (int)MQ, 512, 512, 0);
    short* Qcat = (short*)zoneD;
    fuse_cat<<<dim3(4096), dim3(256), 0, stream>>>(caq_bf, caqp_bf, Qcat, 1024, 10, 512, 512);

    // P9-P11: CA key/value path
    short* cakv_bf = (short*)zoneA;
    short* cakp_bf = (short*)zoneB;
    gemm(kvd_bf, wT_cakv, b_cakv, cakv_bf, nullptr, (int)MK, 1024, 256, 0);
    gemm(kvp_bf, wT_cakp, b_cakp, cakp_bf, nullptr, (int)MK, 512, 256, 0);
    short* Kcat = (short*)zoneG;
    fuse_cat<<<dim3(8192), dim3(256), 0, stream>>>(cakv_bf, cakp_bf, Kcat, 2048, 11, 1024, 512);
    fuse_vt<<<dim3(Kn / 32, 64), dim3(256), 0, stream>>>(cakv_bf, VtCA, 1024, 512, Kn);

    // P12: CA attention
    attn_kernel<128, 2048><<<dim3(512), dim3(256), 0, stream>>>(
        Qcat, Kcat, VtCA, mb_ca, att_f, 0.08838834764831845f * 1.44269504f);

    // P13: LN2
    ln_fuse<<<dim3((unsigned)(MQ / 4)), dim3(256), 0, stream>>>(sa_ln_f, att_f, g_ca, be_ca, ca_ln_f, caln_bf);

    // P14-P15: FFN
    short* mid_bf = (short*)zoneG;
    gemm(caln_bf, wT_f1, b_f1, mid_bf, nullptr, (int)MQ, 2048, 512, 1);
    gemm(mid_bf, wT_f2, b_f2, nullptr, f_out, (int)MQ, 512, 2048, 0);

    // P16: final LN -> d_out
    ln_fuse<<<dim3((unsigned)(MQ / 4)), dim3(256), 0, stream>>>(ca_ln_f, f_out, g_f, be_f, (float*)d_out, (short*)nullptr);
}

// Round 4
// 428.130 us; speedup vs baseline: 1.1661x; 1.0438x over previous
//
#include <hip/hip_runtime.h>

typedef __attribute__((ext_vector_type(4))) float f32x4;
typedef __attribute__((ext_vector_type(8))) short bf16x8;
typedef __attribute__((ext_vector_type(4))) unsigned int u32x4;

static __device__ __forceinline__ float bf2f(short s){
    unsigned int u = ((unsigned int)(unsigned short)s) << 16;
    return __builtin_bit_cast(float, u);
}
static __device__ __forceinline__ short f2bf(float f){
    unsigned int u = __builtin_bit_cast(unsigned int, f);
    unsigned int r = (u + 0x7fffu + ((u >> 16) & 1u)) >> 16;
    return (short)r;
}
static __device__ __forceinline__ void gload_lds16(const void* g, void* l){
    __builtin_amdgcn_global_load_lds((const __attribute__((address_space(1))) void*)g,
                                     (__attribute__((address_space(3))) void*)l, 16, 0, 0);
}
static __device__ __forceinline__ float exp2fast(float x){
    float r; asm("v_exp_f32 %0, %1" : "=v"(r) : "v"(x)); return r;
}
static __device__ __forceinline__ unsigned int packbf(float lo, float hi){
#if __has_builtin(__builtin_amdgcn_perm)
    return __builtin_amdgcn_perm(__builtin_bit_cast(unsigned int, hi),
                                 __builtin_bit_cast(unsigned int, lo), 0x07060302u);
#else
    return (__builtin_bit_cast(unsigned int, hi) & 0xffff0000u) |
           (__builtin_bit_cast(unsigned int, lo) >> 16);
#endif
}

// ---------------- elementwise cast fp32 -> bf16 ----------------
__global__ __launch_bounds__(256) void cast_f32_bf16(const float* __restrict__ in,
                                                     short* __restrict__ out, long n){
    long i = ((long)blockIdx.x * 256 + threadIdx.x) * 8;
    if (i >= n) return;
    f32x4 a = *(const f32x4*)(in + i);
    f32x4 b = *(const f32x4*)(in + i + 4);
    bf16x8 o;
#pragma unroll
    for (int j = 0; j < 4; j++){ o[j] = f2bf(a[j]); o[4 + j] = f2bf(b[j]); }
    *(bf16x8*)(out + i) = o;
}

// ---------------- mask byte -> additive bias (0 / -1e30) ----------------
__global__ __launch_bounds__(256) void build_mbias(const unsigned char* __restrict__ m,
                                                   float* __restrict__ o, int n){
    int i = blockIdx.x * 256 + threadIdx.x;
    if (i < n) o[i] = m[i] ? -1e30f : 0.f;
}

// ---------------- weight transpose-cast: w[K][N] -> wT[N][K] bf16 ----------------
__global__ __launch_bounds__(256) void transcast(const float* __restrict__ w,
                                                 short* __restrict__ wT, int K, int N){
    int n = blockIdx.x * 256 + threadIdx.x;
    int k0 = blockIdx.y * 8;
    bf16x8 o;
#pragma unroll
    for (int j = 0; j < 8; j++) o[j] = f2bf(w[(long)(k0 + j) * N + n]);
    *(bf16x8*)(wT + (long)n * K + k0) = o;
}

// ---------------- GEMM: C[M,N] = A[M,K](bf16) @ Bt[N,K]^T(bf16) + bias ----------------
// 128xBN tile, BK=32, 4 waves (2x2), 16x16x32 MFMA, gload_lds staging, XOR swizzle.
template<int BN>
__global__ __launch_bounds__(256, (BN == 64) ? 4 : 2) void gemm_bf16(
    const short* __restrict__ A, const short* __restrict__ Bt, const float* __restrict__ bias,
    short* __restrict__ Cbf, float* __restrict__ Cf, int M, int N, int K, int doRelu)
{
    constexpr int NI = BN / 32;   // n-frags per wave (2x2 wave grid)
    __shared__ __attribute__((aligned(16))) short lA[128 * 32];
    __shared__ __attribute__((aligned(16))) short lB[BN * 32];
    int t = threadIdx.x, w = t >> 6, l = t & 63;
    int cl = l & 15, g = l >> 4;
    long r0 = (long)blockIdx.y * 128, c0 = (long)blockIdx.x * BN;
    int wr = w >> 1, wc = w & 1;
    f32x4 acc[4][NI];
#pragma unroll
    for (int mi = 0; mi < 4; mi++)
#pragma unroll
        for (int ni = 0; ni < NI; ni++) acc[mi][ni] = f32x4{0.f, 0.f, 0.f, 0.f};
    int srow = t >> 2, sblk = t & 3;
    for (int k0 = 0; k0 < K; k0 += 32){
        __syncthreads();
#pragma unroll
        for (int i = 0; i < 2; i++){
            int rrow = srow + i * 64;
            int sb = sblk ^ (rrow & 3);
            gload_lds16(A + (r0 + rrow) * (long)K + k0 + sb * 8, (char*)lA + i * 4096 + w * 1024);
        }
#pragma unroll
        for (int i = 0; i < BN / 64; i++){
            int rrow = srow + i * 64;
            int sb = sblk ^ (rrow & 3);
            gload_lds16(Bt + (c0 + rrow) * (long)K + k0 + sb * 8, (char*)lB + i * 4096 + w * 1024);
        }
        __syncthreads();
        bf16x8 af[4], bfr[NI];
#pragma unroll
        for (int mi = 0; mi < 4; mi++){
            int row = wr * 64 + mi * 16 + cl;
            af[mi] = *(const bf16x8*)(lA + row * 32 + (g ^ (row & 3)) * 8);
        }
#pragma unroll
        for (int ni = 0; ni < NI; ni++){
            int row = wc * (BN / 2) + ni * 16 + cl;
            bfr[ni] = *(const bf16x8*)(lB + row * 32 + (g ^ (row & 3)) * 8);
        }
#pragma unroll
        for (int mi = 0; mi < 4; mi++)
#pragma unroll
            for (int ni = 0; ni < NI; ni++)
                acc[mi][ni] = __builtin_amdgcn_mfma_f32_16x16x32_bf16(af[mi], bfr[ni], acc[mi][ni], 0, 0, 0);
    }
#pragma unroll
    for (int mi = 0; mi < 4; mi++)
#pragma unroll
        for (int ni = 0; ni < NI; ni++){
            long col = c0 + wc * (BN / 2) + ni * 16 + cl;
            float bv = bias[col];
#pragma unroll
            for (int rr = 0; rr < 4; rr++){
                long rowg = r0 + wr * 64 + mi * 16 + g * 4 + rr;
                float v = acc[mi][ni][rr] + bv;
                if (doRelu) v = fmaxf(v, 0.f);
                long idx = rowg * N + col;
                if (Cbf) Cbf[idx] = f2bf(v);
                if (Cf)  Cf[idx]  = v;
            }
        }
}

// ---------------- SA fuse: Qa/Ka = (qkv q/k) + (pos q/k), head-split [bh][qn][64] ----------------
__global__ __launch_bounds__(256) void fuse_sa_qk(const short* __restrict__ qkv,
                                                  const short* __restrict__ pos,
                                                  short* __restrict__ Qa, short* __restrict__ Ka){
    long i = (long)blockIdx.x * 256 + threadIdx.x;
    long row = i >> 6;
    int c = (int)(i & 63) * 8;
    int h = c >> 6, d = c & 63;
    long b = row >> 10, qn = row & 1023;
    long obase = ((b * 8 + h) * 1024 + qn) * 64 + d;
    bf16x8 q  = *(const bf16x8*)(qkv + row * 1536 + c);
    bf16x8 k  = *(const bf16x8*)(qkv + row * 1536 + 512 + c);
    bf16x8 qp = *(const bf16x8*)(pos + row * 1024 + c);
    bf16x8 kp = *(const bf16x8*)(pos + row * 1024 + 512 + c);
    bf16x8 oq, ok;
#pragma unroll
    for (int j = 0; j < 8; j++){
        oq[j] = f2bf(bf2f(q[j]) + bf2f(qp[j]));
        ok[j] = f2bf(bf2f(k[j]) + bf2f(kp[j]));
    }
    *(bf16x8*)(Qa + obase) = oq;
    *(bf16x8*)(Ka + obase) = ok;
}

// ---------------- V transpose: Vt[bh][dv=64][KN] ----------------
__global__ __launch_bounds__(256) void fuse_vt(const short* __restrict__ src, short* __restrict__ Vt,
                                               int srcStride, int colBase, int KN){
    long bh = blockIdx.y; long b = bh >> 3; int h = (int)bh & 7;
    int dv = threadIdx.x & 63;
    int kn0 = blockIdx.x * 32 + (threadIdx.x >> 6) * 8;
    long base = (b * (long)KN + kn0) * srcStride + colBase + h * 64 + dv;
    bf16x8 o;
#pragma unroll
    for (int j = 0; j < 8; j++) o[j] = src[base + (long)j * srcStride];
    *(bf16x8*)(Vt + (bh * 64 + dv) * (long)KN + kn0) = o;
}

// ---------------- fused residual + LayerNorm (512 cols), wave-per-row ----------------
__global__ __launch_bounds__(256) void ln_fuse(const float* __restrict__ a, const float* __restrict__ b,
                                               const float* __restrict__ g, const float* __restrict__ be,
                                               float* __restrict__ outf, short* __restrict__ outb){
    int w = threadIdx.x >> 6, l = threadIdx.x & 63;
    long row = (long)blockIdx.x * 4 + w;
    long base = row * 512 + l * 8;
    f32x4 a0 = *(const f32x4*)(a + base);
    f32x4 a1 = *(const f32x4*)(a + base + 4);
    f32x4 b0 = *(const f32x4*)(b + base);
    f32x4 b1 = *(const f32x4*)(b + base + 4);
    float x[8]; float s = 0.f, s2 = 0.f;
#pragma unroll
    for (int j = 0; j < 4; j++){ x[j] = a0[j] + b0[j]; x[4 + j] = a1[j] + b1[j]; }
#pragma unroll
    for (int j = 0; j < 8; j++){ s += x[j]; s2 += x[j] * x[j]; }
#pragma unroll
    for (int o = 1; o < 64; o <<= 1){ s += __shfl_xor(s, o); s2 += __shfl_xor(s2, o); }
    float mean = s * (1.f / 512.f);
    float rstd = rsqrtf(s2 * (1.f / 512.f) - mean * mean + 1e-5f);
    int c = l * 8;
    f32x4 y0, y1; bf16x8 ob;
#pragma unroll
    for (int j = 0; j < 4; j++){
        float y = (x[j] - mean) * rstd * g[c + j] + be[c + j];
        y0[j] = y; ob[j] = f2bf(y);
    }
#pragma unroll
    for (int j = 0; j < 4; j++){
        float y = (x[4 + j] - mean) * rstd * g[c + 4 + j] + be[c + 4 + j];
        y1[j] = y; ob[4 + j] = f2bf(y);
    }
    *(f32x4*)(outf + base) = y0;
    *(f32x4*)(outf + base + 4) = y1;
    if (outb) *(bf16x8*)(outb + base) = ob;
}

// ---------------- flash attention v3 ----------------
// 8 waves x 16 q-rows = 128 q/block; double-buffered prefetch (stage t+1 before compute t,
// one barrier per tile); mfma32 with permuted key order; log2-domain softmax.
// CAT=false: Q1[bh][Qn][DH], K1[bh][KN][DH].
// CAT=true (CA): Q = concat(Q1[b][Qn][512]+h*64, Q2 same); K = concat(K1[b][KN][1024]+h*64,
//                K2[b][KN][512]+h*64)  -- concat fused into loads.
// Vt[bh][64][KN]; mbias[b][KN]; out[b][q][h*64+dv] fp32.
template<int DH, int KN, bool CAT>
__global__ __launch_bounds__(512, 4) void attn_kernel(
    const short* __restrict__ Q1, const short* __restrict__ Q2,
    const short* __restrict__ K1, const short* __restrict__ K2,
    const short* __restrict__ Vt,
    const float* __restrict__ mbias, float* __restrict__ out, float scale2)
{
    constexpr int KT = 64, DV = 64, Qn = 1024, H = 8;
    constexpr int NF = DH / 32;            // mfma k-steps (4 or 2)
    constexpr int BPR = DH / 8;            // 16B blocks per K row (16 or 8)
    constexpr int KITER = KT * BPR / 512;  // K staging iters (2 or 1)
    constexpr int NT = KN / KT;
    __shared__ __attribute__((aligned(16))) short lK[2][KT * DH];
    __shared__ __attribute__((aligned(16))) short lV[2][DV * KT];
    int t = threadIdx.x, w = t >> 6, l = t & 63;
    int cl = l & 15, g = l >> 4;
    // XCD-aware bijective swizzle: 512 blocks, 8 XCDs -> each XCD owns 8 consecutive bh
    int bid = blockIdx.x;
    int bh = (bid & 7) * 8 + (bid >> 6);
    int qb = (bid >> 3) & 7;
    int b = bh >> 3, h = bh & 7;
    int q0 = qb * 128 + w * 16;

    bf16x8 qf[NF];
#pragma unroll
    for (int f = 0; f < NF; f++){
        if constexpr (CAT){
            const short* src = (f < NF / 2) ? Q1 : Q2;
            qf[f] = *(const bf16x8*)(src + ((long)b * Qn + q0 + cl) * 512 + h * 64
                                     + (f & (NF / 2 - 1)) * 32 + 8 * g);
        } else {
            qf[f] = *(const bf16x8*)(Q1 + ((long)bh * Qn + q0 + cl) * DH + f * 32 + 8 * g);
        }
    }

    auto stage = [&](int d, int key0){
#pragma unroll
        for (int i = 0; i < KITER; i++){
            int s = i * 512 + t;
            int srow = s / BPR, blk = s % BPR;
            int s32 = srow & 31;
            int key = (srow & 32) + 8 * ((s32 >> 2) & 3) + 4 * (s32 >> 4) + (s32 & 3);
            int sb = blk ^ (srow & 7);
            const short* src;
            if constexpr (CAT){
                src = (sb < 8) ? K1 + ((long)(b * KN + key0 + key)) * 1024 + h * 64 + sb * 8
                               : K2 + ((long)(b * KN + key0 + key)) * 512 + h * 64 + (sb - 8) * 8;
            } else {
                src = K1 + ((long)bh * KN + key0 + key) * DH + sb * 8;
            }
            gload_lds16(src, (char*)(&lK[d][0]) + i * 8192 + w * 1024);
        }
        {
            int srow = t >> 3, blk = t & 7;
            int sb = blk ^ (srow & 7);
            gload_lds16(Vt + ((long)bh * DV + srow) * KN + key0 + sb * 8,
                        (char*)(&lV[d][0]) + w * 1024);
        }
    };

    const float* mrow = mbias + (long)b * KN;
    float m = -1e30f, ssum = 0.f;
    f32x4 oacc[4];
#pragma unroll
    for (int d = 0; d < 4; d++) oacc[d] = f32x4{0.f, 0.f, 0.f, 0.f};

    stage(0, 0);
    __syncthreads();

    for (int tt = 0; tt < NT; tt++){
        int cur = tt & 1;
        int key0 = tt * KT;
        if (tt + 1 < NT) stage(cur ^ 1, key0 + KT);   // prefetch next tile (async, other buffer)

        // QK^T: 4 outputs x NF k-steps
        f32x4 st[4];
#pragma unroll
        for (int o = 0; o < 4; o++){
            int srow = o * 16 + cl;
            f32x4 acc = f32x4{0.f, 0.f, 0.f, 0.f};
#pragma unroll
            for (int f = 0; f < NF; f++){
                int sb = (4 * f + g) ^ (srow & 7);
                bf16x8 kf = *(const bf16x8*)(&lK[cur][0] + srow * DH + sb * 8);
                acc = __builtin_amdgcn_mfma_f32_16x16x32_bf16(kf, qf[f], acc, 0, 0, 0);
            }
            st[o] = acc;
        }
        // softmax (lane's key for (o,rr): (o>>1)*32 + 8g + 4*(o&1) + rr; q = cl)
        f32x4 mb[4];
#pragma unroll
        for (int o = 0; o < 4; o++)
            mb[o] = *(const f32x4*)(mrow + key0 + (o >> 1) * 32 + 8 * g + 4 * (o & 1));
        f32x4 s2[4];
        float tm = -1e30f;
#pragma unroll
        for (int o = 0; o < 4; o++){
#pragma unroll
            for (int rr = 0; rr < 4; rr++)
                s2[o][rr] = fmaf(st[o][rr], scale2, mb[o][rr]);
            tm = fmaxf(tm, fmaxf(fmaxf(s2[o][0], s2[o][1]), fmaxf(s2[o][2], s2[o][3])));
        }
        tm = fmaxf(tm, __shfl_xor(tm, 16));
        tm = fmaxf(tm, __shfl_xor(tm, 32));
        float mnew = fmaxf(m, tm);
        float fac = exp2fast(m - mnew);
        float rs = 0.f;
        bf16x8 pa[2];
#pragma unroll
        for (int kb = 0; kb < 2; kb++){
            float pA[4], pB[4];
#pragma unroll
            for (int rr = 0; rr < 4; rr++){
                pA[rr] = exp2fast(s2[2 * kb][rr] - mnew);
                pB[rr] = exp2fast(s2[2 * kb + 1][rr] - mnew);
                rs += pA[rr] + pB[rr];
            }
            u32x4 pk;
            pk[0] = packbf(pA[0], pA[1]);
            pk[1] = packbf(pA[2], pA[3]);
            pk[2] = packbf(pB[0], pB[1]);
            pk[3] = packbf(pB[2], pB[3]);
            pa[kb] = __builtin_bit_cast(bf16x8, pk);
        }
        rs += __shfl_xor(rs, 16);
        rs += __shfl_xor(rs, 32);
        ssum = ssum * fac + rs;
        m = mnew;
        float fr[4];
#pragma unroll
        for (int rr = 0; rr < 4; rr++) fr[rr] = __shfl(fac, 4 * g + rr);
        // PV
#pragma unroll
        for (int dvc = 0; dvc < 4; dvc++){
            int vrow = dvc * 16 + cl;
            bf16x8 vf[2];
#pragma unroll
            for (int kb = 0; kb < 2; kb++){
                int sb = (4 * kb + g) ^ (vrow & 7);
                vf[kb] = *(const bf16x8*)(&lV[cur][0] + vrow * KT + sb * 8);
            }
            f32x4 o = oacc[dvc];
#pragma unroll
            for (int rr = 0; rr < 4; rr++) o[rr] *= fr[rr];
            o = __builtin_amdgcn_mfma_f32_16x16x32_bf16(pa[0], vf[0], o, 0, 0, 0);
            o = __builtin_amdgcn_mfma_f32_16x16x32_bf16(pa[1], vf[1], o, 0, 0, 0);
            oacc[dvc] = o;
        }
        __syncthreads();   // drains prefetch vmcnt + all lgkm; next buffer ready
    }

    float linv[4];
#pragma unroll
    for (int rr = 0; rr < 4; rr++) linv[rr] = 1.f / __shfl(ssum, 4 * g + rr);
#pragma unroll
    for (int dvc = 0; dvc < 4; dvc++)
#pragma unroll
        for (int rr = 0; rr < 4; rr++){
            int q = q0 + 4 * g + rr;
            out[(((long)b * Qn + q) * H + h) * DV + dvc * 16 + cl] = oacc[dvc][rr] * linv[rr];
        }
}

// ================= host orchestration =================
extern "C" void kernel_launch(void* const* d_in, const int* in_sizes, int n_in,
                              void* d_out, int out_size, void* d_ws, size_t ws_size,
                              hipStream_t stream)
{
    (void)in_sizes; (void)n_in; (void)out_size; (void)ws_size;
    const int Qn = 1024, Kn = 2048;
    const long MQ = 8L * Qn;   // 8192
    const long MK = 8L * Kn;   // 16384

    const float* queries = (const float*)d_in[0];
    const unsigned char* qmask = (const unsigned char*)d_in[1];
    const float* box  = (const float*)d_in[2];
    const float* ctr  = (const float*)d_in[3];
    const float* kvd  = (const float*)d_in[4];
    const unsigned char* kmask = (const unsigned char*)d_in[5];
    const float* kvp  = (const float*)d_in[6];
    const float* w_qkv = (const float*)d_in[7];  const float* b_qkv = (const float*)d_in[8];
    const float* w_pos = (const float*)d_in[9];  const float* b_pos = (const float*)d_in[10];
    const float* g_sa  = (const float*)d_in[11]; const float* be_sa = (const float*)d_in[12];
    const float* w_caq = (const float*)d_in[13]; const float* b_caq = (const float*)d_in[14];
    const float* w_cakv = (const float*)d_in[15]; const float* b_cakv = (const float*)d_in[16];
    const float* w_caqp = (const float*)d_in[17]; const float* b_caqp = (const float*)d_in[18];
    const float* w_cakp = (const float*)d_in[19]; const float* b_cakp = (const float*)d_in[20];
    const float* g_ca  = (const float*)d_in[21]; const float* be_ca = (const float*)d_in[22];
    const float* w_f1  = (const float*)d_in[23]; const float* b_f1 = (const float*)d_in[24];
    const float* w_f2  = (const float*)d_in[25]; const float* b_f2 = (const float*)d_in[26];
    const float* g_f   = (const float*)d_in[27]; const float* be_f = (const float*)d_in[28];

    char* ws = (char*)d_ws;
    size_t off = 0;
    auto alloc = [&](size_t bytes) -> char* {
        char* p = ws + off;
        off += (bytes + 255) & ~(size_t)255;
        return p;
    };
    short* wT_qkv  = (short*)alloc(1536L * 512 * 2);
    short* wT_pos  = (short*)alloc(1024L * 1024 * 2);
    short* wT_caq  = (short*)alloc(512L * 512 * 2);
    short* wT_cakv = (short*)alloc(1024L * 256 * 2);
    short* wT_caqp = (short*)alloc(512L * 512 * 2);
    short* wT_cakp = (short*)alloc(512L * 256 * 2);
    short* wT_f1   = (short*)alloc(2048L * 512 * 2);
    short* wT_f2   = (short*)alloc(512L * 2048 * 2);
    short* ctr_bf  = (short*)alloc(MQ * 512 * 2);
    short* kvd_bf  = (short*)alloc(MK * 256 * 2);
    short* kvp_bf  = (short*)alloc(MK * 256 * 2);
    short* saln_bf = (short*)alloc(MQ * 512 * 2);
    short* caln_bf = (short*)alloc(MQ * 512 * 2);
    float* sa_ln_f = (float*)alloc(MQ * 512 * 4);
    float* ca_ln_f = (float*)alloc(MQ * 512 * 4);
    float* att_f   = (float*)alloc(MQ * 512 * 4);
    float* f_out   = (float*)alloc(MQ * 512 * 4);
    short* VtSA    = (short*)alloc(64L * 64 * 1024 * 2);
    short* VtCA    = (short*)alloc(64L * 64 * 2048 * 2);
    float* mb_sa   = (float*)alloc(MQ * 4);
    float* mb_ca   = (float*)alloc(MK * 4);
    char* zoneA = alloc(MQ * 1536 * 2);          // qkv_bf | cakv_bf
    char* zoneB = alloc(MQ * 1024 * 2);          // pos_bf | cakp_bf
    char* zoneC = alloc(MQ * 512 * 2);           // xq_bf | caq_bf
    char* zoneD = alloc(MQ * 1024 * 2);          // box_bf
    char* zoneE = alloc(MQ * 512 * 2);           // Qa | caqp_bf
    char* zoneF = alloc(MQ * 512 * 2);           // Ka
    char* zoneG = alloc(MQ * 2048 * 2);          // mid_bf

    auto cast = [&](const float* src, short* dst, long n){
        cast_f32_bf16<<<dim3((unsigned)(n / 8 / 256)), dim3(256), 0, stream>>>(src, dst, n);
    };
    auto trans = [&](const float* wsrc, short* wT, int K, int N){
        transcast<<<dim3(N / 256, K / 8), dim3(256), 0, stream>>>(wsrc, wT, K, N);
    };
    auto gemm128 = [&](const short* A, const short* Bt, const float* bias, short* Cbf, float* Cf,
                       int M, int N, int K, int relu){
        gemm_bf16<128><<<dim3(N / 128, M / 128), dim3(256), 0, stream>>>(A, Bt, bias, Cbf, Cf, M, N, K, relu);
    };
    auto gemm64 = [&](const short* A, const short* Bt, const float* bias, short* Cbf, float* Cf,
                      int M, int N, int K, int relu){
        gemm_bf16<64><<<dim3(N / 64, M / 128), dim3(256), 0, stream>>>(A, Bt, bias, Cbf, Cf, M, N, K, relu);
    };

    // P0: casts + weight transposes + mask bias
    short* xq_bf  = (short*)zoneC;
    short* box_bf = (short*)zoneD;
    cast(queries, xq_bf, MQ * 512);
    cast(box, box_bf, MQ * 1024);
    cast(ctr, ctr_bf, MQ * 512);
    cast(kvd, kvd_bf, MK * 256);
    cast(kvp, kvp_bf, MK * 256);
    build_mbias<<<dim3(32), dim3(256), 0, stream>>>(qmask, mb_sa, (int)MQ);
    build_mbias<<<dim3(64), dim3(256), 0, stream>>>(kmask, mb_ca, (int)MK);
    trans(w_qkv, wT_qkv, 512, 1536);
    trans(w_pos, wT_pos, 1024, 1024);
    trans(w_caq, wT_caq, 512, 512);
    trans(w_cakv, wT_cakv, 256, 1024);
    trans(w_caqp, wT_caqp, 512, 512);
    trans(w_cakp, wT_cakp, 256, 512);
    trans(w_f1, wT_f1, 512, 2048);
    trans(w_f2, wT_f2, 2048, 512);

    // P1-P2: SA projections
    short* qkv_bf = (short*)zoneA;
    short* pos_bf = (short*)zoneB;
    gemm128(xq_bf, wT_qkv, b_qkv, qkv_bf, nullptr, (int)MQ, 1536, 512, 0);
    gemm128(box_bf, wT_pos, b_pos, pos_bf, nullptr, (int)MQ, 1024, 1024, 0);

    // P3: SA fuse
    short* Qa = (short*)zoneE;
    short* Ka = (short*)zoneF;
    fuse_sa_qk<<<dim3(2048), dim3(256), 0, stream>>>(qkv_bf, pos_bf, Qa, Ka);
    fuse_vt<<<dim3(Qn / 32, 64), dim3(256), 0, stream>>>(qkv_bf, VtSA, 1536, 1024, Qn);

    // P4: SA attention
    attn_kernel<64, 1024, false><<<dim3(512), dim3(512), 0, stream>>>(
        Qa, nullptr, Ka, nullptr, VtSA, mb_sa, att_f, 0.125f * 1.44269504f);

    // P5: LN1
    ln_fuse<<<dim3((unsigned)(MQ / 4)), dim3(256), 0, stream>>>(queries, att_f, g_sa, be_sa, sa_ln_f, saln_bf);

    // P6-P7: CA query path (concat fused into attention loads)
    short* caq_bf  = (short*)zoneC;
    short* caqp_bf = (short*)zoneE;
    gemm64(saln_bf, wT_caq, b_caq, caq_bf, nullptr, (int)MQ, 512, 512, 0);
    gemm64(ctr_bf, wT_caqp, b_caqp, caqp_bf, nullptr, (int)MQ, 512, 512, 0);

    // P8-P9: CA key/value path
    short* cakv_bf = (short*)zoneA;
    short* cakp_bf = (short*)zoneB;
    gemm128(kvd_bf, wT_cakv, b_cakv, cakv_bf, nullptr, (int)MK, 1024, 256, 0);
    gemm128(kvp_bf, wT_cakp, b_cakp, cakp_bf, nullptr, (int)MK, 512, 256, 0);
    fuse_vt<<<dim3(Kn / 32, 64), dim3(256), 0, stream>>>(cakv_bf, VtCA, 1024, 512, Kn);

    // P10: CA attention (reads caq/caqp + cakv/cakp directly)
    attn_kernel<128, 2048, true><<<dim3(512), dim3(512), 0, stream>>>(
        caq_bf, caqp_bf, cakv_bf, cakp_bf, VtCA, mb_ca, att_f, 0.08838834764831845f * 1.44269504f);

    // P11: LN2
    ln_fuse<<<dim3((unsigned)(MQ / 4)), dim3(256), 0, stream>>>(sa_ln_f, att_f, g_ca, be_ca, ca_ln_f, caln_bf);

    // P12-P13: FFN
    short* mid_bf = (short*)zoneG;
    gemm128(caln_bf, wT_f1, b_f1, mid_bf, nullptr, (int)MQ, 2048, 512, 1);
    gemm64(mid_bf, wT_f2, b_f2, nullptr, f_out, (int)MQ, 512, 2048, 0);

    // P14: final LN -> d_out
    ln_fuse<<<dim3((unsigned)(MQ / 4)), dim3(256), 0, stream>>>(ca_ln_f, f_out, g_f, be_f, (float*)d_out, (short*)nullptr);
}